// Round 2
// baseline (341.400 us; speedup 1.0000x reference)
//
#include <hip/hip_runtime.h>

// RyeElman fused cell, MI355X. B=131072, I=64, H=128, C=16, S=3.
// All four matmuls via v_mfma_f32_16x16x32_f16, f32 accumulate.
// Weights register-resident (B-fragments); 16 rows/iter staged through LDS.
// R2: coalesced out0 store via proj_s round-trip (was 4x HBM write
// amplification from 64B C-layout segments); register prefetch of next
// tile's inputs; merged norm+build phase (4 barriers/tile).

typedef _Float16 half8  __attribute__((ext_vector_type(8)));
typedef _Float16 half4v __attribute__((ext_vector_type(4)));
typedef float    float4v __attribute__((ext_vector_type(4)));

#define MFMA16(A, Bv, C) __builtin_amdgcn_mfma_f32_16x16x32_f16((A), (Bv), (C), 0, 0, 0)

#define N_TILES 8192   // 131072 / 16 rows per tile
#define GRID    2048   // 4 tiles per block

__global__ void rye_elman_kernel(
    const float* __restrict__ inv_in,   // [B,64]
    const float* __restrict__ eq_in,    // [B,3]
    const float* __restrict__ inv_hid,  // [B,128]
    const float* __restrict__ eq_hid,   // [B,3,16]
    const float* __restrict__ Wl_g,     // [17,128]
    const float* __restrict__ Wr_g,     // [17,128]
    const float* __restrict__ Wii_g,    // [192,128]
    const float* __restrict__ bii_g,    // [128]
    const float* __restrict__ Wee_g,    // [17,16]
    const float* __restrict__ Wd_g,     // [192,16]
    float* __restrict__ out0,           // [B,128]
    float* __restrict__ out1)           // [B,3,16]
{
    __shared__ __align__(16) _Float16 A_ii[16][200];  // inv_comb rows, f16
    __shared__ __align__(16) _Float16 A_xn[16][136];  // xn, [4 s-slots][32 k], pads zero
    __shared__ __align__(16) _Float16 A_rw[16][136];  // raw eq_comb, same layout
    __shared__ float eqin_s[16][3];
    __shared__ __align__(16) float eh_s[16][48];      // exact f32 eq_hid for damping
    __shared__ __align__(16) float proj_s[16][132];   // proj, then final out0 tile
    __shared__ float ee_s[16][52];
    __shared__ float gate_s[16][16];

    const int tid  = threadIdx.x;
    const int w    = tid >> 6;   // wave 0..3, owns H-cols [32w,32w+32)
    const int lane = tid & 63;
    const int q    = lane >> 4;  // k-chunk / C-row group
    const int m    = lane & 15;  // A-row / B-col within 16

    // zero A_xn/A_rw once: MFMA correctness relies on s==3 and k>=17 pads being 0
    {
        unsigned* z0 = (unsigned*)&A_xn[0][0];
        unsigned* z1 = (unsigned*)&A_rw[0][0];
        for (int i = tid; i < 16 * 136 / 2; i += 256) { z0[i] = 0u; z1[i] = 0u; }
    }

    // ---- register-resident weight B-fragments: B[n=lane&15][k=(lane>>4)*8+j]
    half8 wii[2][6], wl[2], wr[2], wdamp[6], wee;
    float biiv[2];
#pragma unroll
    for (int t = 0; t < 2; ++t) {
        const int col = 32 * w + 16 * t + m;
        biiv[t] = bii_g[col];
#pragma unroll
        for (int s = 0; s < 6; ++s) {
            half8 u;
#pragma unroll
            for (int j = 0; j < 8; ++j)
                u[j] = (_Float16)Wii_g[(32 * s + 8 * q + j) * 128 + col];
            wii[t][s] = u;
        }
        half8 ul, ur;
#pragma unroll
        for (int j = 0; j < 8; ++j) {
            const int k = 8 * q + j;
            ul[j] = (k < 17) ? (_Float16)Wl_g[k * 128 + col] : (_Float16)0.f;
            ur[j] = (k < 17) ? (_Float16)Wr_g[k * 128 + col] : (_Float16)0.f;
        }
        wl[t] = ul; wr[t] = ur;
    }
#pragma unroll
    for (int s = 0; s < 6; ++s) {
        half8 u;
#pragma unroll
        for (int j = 0; j < 8; ++j)
            u[j] = (_Float16)Wd_g[(32 * s + 8 * q + j) * 16 + m];
        wdamp[s] = u;
    }
    {
        half8 u;
#pragma unroll
        for (int j = 0; j < 8; ++j) {
            const int k = 8 * q + j;
            u[j] = (k < 17) ? (_Float16)Wee_g[k * 16 + m] : (_Float16)0.f;
        }
        wee = u;
    }
    __syncthreads();

    // ---- prefetch registers for software pipeline
    float4 p_inv, p_hid0, p_hid1, p_eh;
    float  p_eq;

#define LOAD_TILE(BASE)                                                     \
    do {                                                                    \
        const long _b = (BASE);                                             \
        p_inv  = ((const float4*)(inv_in  + _b * 64))[tid];                 \
        p_hid0 = ((const float4*)(inv_hid + _b * 128))[tid];                \
        p_hid1 = ((const float4*)(inv_hid + _b * 128))[tid + 256];          \
        if (tid < 192) p_eh = ((const float4*)(eq_hid + _b * 48))[tid];     \
        if (tid < 48)  p_eq = eq_in[_b * 3 + tid];                          \
    } while (0)

    LOAD_TILE((long)blockIdx.x * 16);

    for (int tile = blockIdx.x; tile < N_TILES; tile += GRID) {
        const long base = (long)tile * 16;

        // ---- commit prefetched regs -> LDS (f32->f16 convert for A operands)
        if (tid < 48) eqin_s[tid / 3][tid % 3] = p_eq;
        if (tid < 192) *(float4*)&eh_s[tid / 12][(tid % 12) * 4] = p_eh;
        {
            half4v h; h[0] = (_Float16)p_inv.x; h[1] = (_Float16)p_inv.y;
                      h[2] = (_Float16)p_inv.z; h[3] = (_Float16)p_inv.w;
            *(half4v*)&A_ii[tid >> 4][(tid & 15) * 4] = h;
        }
        {
            half4v h; h[0] = (_Float16)p_hid0.x; h[1] = (_Float16)p_hid0.y;
                      h[2] = (_Float16)p_hid0.z; h[3] = (_Float16)p_hid0.w;
            *(half4v*)&A_ii[tid >> 5][64 + (tid & 31) * 4] = h;
            const int i1 = tid + 256;
            half4v g; g[0] = (_Float16)p_hid1.x; g[1] = (_Float16)p_hid1.y;
                      g[2] = (_Float16)p_hid1.z; g[3] = (_Float16)p_hid1.w;
            *(half4v*)&A_ii[i1 >> 5][64 + (i1 & 31) * 4] = g;
        }
        __syncthreads();                                   // barrier A

        // ---- issue next tile's global loads (consumed at next commit)
        if (tile + GRID < N_TILES) LOAD_TILE((long)(tile + GRID) * 16);

        // ---- build A_rw / A_xn with inline norm recompute
        for (int t = tid; t < 816; t += 256) {
            const int r = t / 51, rem = t % 51;
            const int s = rem / 17, c = rem % 17;
            float x0, x1, x2;
            if (c == 0) { x0 = eqin_s[r][0]; x1 = eqin_s[r][1]; x2 = eqin_s[r][2]; }
            else        { x0 = eh_s[r][c - 1]; x1 = eh_s[r][15 + c]; x2 = eh_s[r][31 + c]; }
            const float a  = fmaf(x0, x0, fmaf(x1, x1, fmaf(x2, x2, 1e-6f)));
            const float rn = __builtin_amdgcn_rcpf(a);
            const float x  = (s == 0) ? x0 : (s == 1) ? x1 : x2;
            A_rw[r][s * 32 + c] = (_Float16)x;
            A_xn[r][s * 32 + c] = (_Float16)(x * rn);
        }
        __syncthreads();                                   // barrier B

        // ---- MFMAs. A-frag: A[m=lane&15][k=(lane>>4)*8+j]
        float4v acc[2] = {{0.f,0.f,0.f,0.f},{0.f,0.f,0.f,0.f}};
        float4v accg   = {0.f,0.f,0.f,0.f};
#pragma unroll
        for (int s = 0; s < 6; ++s) {
            half8 a = *(const half8*)&A_ii[m][8 * q + 32 * s];
            acc[0] = MFMA16(a, wii[0][s], acc[0]);
            acc[1] = MFMA16(a, wii[1][s], acc[1]);
            if (w == 0) accg = MFMA16(a, wdamp[s], accg);   // gate = inv_comb @ W_damp
        }
        const float4v z4 = {0.f,0.f,0.f,0.f};
#pragma unroll
        for (int g = 0; g < 4; ++g) {           // 4 batches per MFMA (rows = 4*bb+s)
            const int arow = 4 * g + (m >> 2);
            const int aoff = (m & 3) * 32 + 8 * q;
            half8 ax = *(const half8*)&A_xn[arow][aoff];
#pragma unroll
            for (int t = 0; t < 2; ++t) {
                float4v L = MFMA16(ax, wl[t], z4);
                float4v R = MFMA16(ax, wr[t], z4);
                // C rows (lane>>4)*4+reg = 4*bb+s : bb=q, s=reg -> s-sum in-register
                proj_s[4 * g + q][32 * w + 16 * t + m] =
                    L[0]*R[0] + L[1]*R[1] + L[2]*R[2];
            }
            if (w == 1) {                        // ee = eq_comb @ W_ee
                half8 ar = *(const half8*)&A_rw[arow][aoff];
                float4v E = MFMA16(ar, wee, z4);
                ee_s[4 * g + q][m]      = E[0];
                ee_s[4 * g + q][16 + m] = E[1];
                ee_s[4 * g + q][32 + m] = E[2];
            }
        }
        if (w == 0) {
#pragma unroll
            for (int r = 0; r < 4; ++r) gate_s[4 * q + r][m] = accg[r];
        }
        __syncthreads();                                   // barrier C

        // ---- out0 epilogue in C-layout: tanh(ii + proj + b) written back
        // into the SAME proj_s slot (no cross-thread hazard)
#pragma unroll
        for (int t = 0; t < 2; ++t) {
            const int col = 32 * w + 16 * t + m;
#pragma unroll
            for (int r = 0; r < 4; ++r) {
                const float x = acc[t][r] + proj_s[4 * q + r][col] + biiv[t];
                const float e = __expf(2.f * x);          // tanh = 1 - 2/(e^{2x}+1)
                proj_s[4 * q + r][col] = 1.f - 2.f * __builtin_amdgcn_rcpf(e + 1.f);
            }
        }
        // ---- out1: ee + eq_hid * gate (exact f32 eq_hid), contiguous
        for (int i = tid; i < 768; i += 256) {
            const int b = i / 48, j = i % 48;
            out1[base * 48 + i] = ee_s[b][j] + eh_s[b][j] * gate_s[b][j & 15];
        }
        __syncthreads();                                   // barrier D

        // ---- out0 coalesced store: 2048 contiguous floats, float4/thread
        {
            const long ob = base * 128;
#pragma unroll
            for (int h = 0; h < 2; ++h) {
                const int idx = (tid + 256 * h) * 4;       // 0..2044 step 4
                const int r = idx >> 7, c = idx & 127;
                float4 v = *(const float4*)&proj_s[r][c];
                *(float4*)&out0[ob + idx] = v;
            }
        }
        // next iteration's LDS writes are ordered by barriers A'/B' after
        // this read of proj_s — no extra barrier needed
    }
#undef LOAD_TILE
}

extern "C" void kernel_launch(void* const* d_in, const int* in_sizes, int n_in,
                              void* d_out, int out_size, void* d_ws, size_t ws_size,
                              hipStream_t stream) {
    const float* inv_in  = (const float*)d_in[0];
    const float* eq_in   = (const float*)d_in[1];
    const float* inv_hid = (const float*)d_in[2];
    const float* eq_hid  = (const float*)d_in[3];
    const float* Wl      = (const float*)d_in[4];
    const float* Wr      = (const float*)d_in[5];
    const float* Wii     = (const float*)d_in[6];
    const float* bii     = (const float*)d_in[7];
    const float* Wee     = (const float*)d_in[8];
    const float* Wd      = (const float*)d_in[9];
    float* o0 = (float*)d_out;
    float* o1 = o0 + (size_t)131072 * 128;
    hipLaunchKernelGGL(rye_elman_kernel, dim3(GRID), dim3(256), 0, stream,
                       inv_in, eq_in, inv_hid, eq_hid, Wl, Wr, Wii, bii, Wee, Wd, o0, o1);
}

// Round 3
// 246.468 us; speedup vs baseline: 1.3852x; 1.3852x over previous
//
#include <hip/hip_runtime.h>

// RyeElman fused cell, MI355X. B=131072, I=64, H=128, C=16, S=3.
// All four matmuls via v_mfma_f32_16x16x32_f16, f32 accumulate.
// Weights register-resident (B-fragments); 16 rows/iter staged through LDS.
// R3: __launch_bounds__(256,2). R1/R2 showed VGPR_Count=64 -> the ~94
// register-resident weight VGPRs were spilling through scratch every tile
// (extra ~270MB HBM write, ~70MB fetch). Budget 512/2=256 VGPR eliminates it.

typedef _Float16 half8  __attribute__((ext_vector_type(8)));
typedef _Float16 half4v __attribute__((ext_vector_type(4)));
typedef float    float4v __attribute__((ext_vector_type(4)));

#define MFMA16(A, Bv, C) __builtin_amdgcn_mfma_f32_16x16x32_f16((A), (Bv), (C), 0, 0, 0)

#define N_TILES 8192   // 131072 / 16 rows per tile
#define GRID    2048   // 4 tiles per block

__global__ __launch_bounds__(256, 2) void rye_elman_kernel(
    const float* __restrict__ inv_in,   // [B,64]
    const float* __restrict__ eq_in,    // [B,3]
    const float* __restrict__ inv_hid,  // [B,128]
    const float* __restrict__ eq_hid,   // [B,3,16]
    const float* __restrict__ Wl_g,     // [17,128]
    const float* __restrict__ Wr_g,     // [17,128]
    const float* __restrict__ Wii_g,    // [192,128]
    const float* __restrict__ bii_g,    // [128]
    const float* __restrict__ Wee_g,    // [17,16]
    const float* __restrict__ Wd_g,     // [192,16]
    float* __restrict__ out0,           // [B,128]
    float* __restrict__ out1)           // [B,3,16]
{
    __shared__ __align__(16) _Float16 A_ii[16][200];  // inv_comb rows, f16
    __shared__ __align__(16) _Float16 A_xn[16][136];  // xn, [4 s-slots][32 k], pads zero
    __shared__ __align__(16) _Float16 A_rw[16][136];  // raw eq_comb, same layout
    __shared__ float eqin_s[16][3];
    __shared__ __align__(16) float eh_s[16][48];      // exact f32 eq_hid for damping
    __shared__ __align__(16) float proj_s[16][132];   // proj, then final out0 tile
    __shared__ float ee_s[16][52];
    __shared__ float gate_s[16][16];

    const int tid  = threadIdx.x;
    const int w    = tid >> 6;   // wave 0..3, owns H-cols [32w,32w+32)
    const int lane = tid & 63;
    const int q    = lane >> 4;  // k-chunk / C-row group
    const int m    = lane & 15;  // A-row / B-col within 16

    // zero A_xn/A_rw once: MFMA correctness relies on s==3 and k>=17 pads being 0
    {
        unsigned* z0 = (unsigned*)&A_xn[0][0];
        unsigned* z1 = (unsigned*)&A_rw[0][0];
        for (int i = tid; i < 16 * 136 / 2; i += 256) { z0[i] = 0u; z1[i] = 0u; }
    }

    // ---- register-resident weight B-fragments: B[n=lane&15][k=(lane>>4)*8+j]
    half8 wii[2][6], wl[2], wr[2], wdamp[6], wee;
    float biiv[2];
#pragma unroll
    for (int t = 0; t < 2; ++t) {
        const int col = 32 * w + 16 * t + m;
        biiv[t] = bii_g[col];
#pragma unroll
        for (int s = 0; s < 6; ++s) {
            half8 u;
#pragma unroll
            for (int j = 0; j < 8; ++j)
                u[j] = (_Float16)Wii_g[(32 * s + 8 * q + j) * 128 + col];
            wii[t][s] = u;
        }
        half8 ul, ur;
#pragma unroll
        for (int j = 0; j < 8; ++j) {
            const int k = 8 * q + j;
            ul[j] = (k < 17) ? (_Float16)Wl_g[k * 128 + col] : (_Float16)0.f;
            ur[j] = (k < 17) ? (_Float16)Wr_g[k * 128 + col] : (_Float16)0.f;
        }
        wl[t] = ul; wr[t] = ur;
    }
#pragma unroll
    for (int s = 0; s < 6; ++s) {
        half8 u;
#pragma unroll
        for (int j = 0; j < 8; ++j)
            u[j] = (_Float16)Wd_g[(32 * s + 8 * q + j) * 16 + m];
        wdamp[s] = u;
    }
    {
        half8 u;
#pragma unroll
        for (int j = 0; j < 8; ++j) {
            const int k = 8 * q + j;
            u[j] = (k < 17) ? (_Float16)Wee_g[k * 16 + m] : (_Float16)0.f;
        }
        wee = u;
    }
    __syncthreads();

    // ---- prefetch registers for software pipeline
    float4 p_inv, p_hid0, p_hid1, p_eh;
    float  p_eq;

#define LOAD_TILE(BASE)                                                     \
    do {                                                                    \
        const long _b = (BASE);                                             \
        p_inv  = ((const float4*)(inv_in  + _b * 64))[tid];                 \
        p_hid0 = ((const float4*)(inv_hid + _b * 128))[tid];                \
        p_hid1 = ((const float4*)(inv_hid + _b * 128))[tid + 256];          \
        if (tid < 192) p_eh = ((const float4*)(eq_hid + _b * 48))[tid];     \
        if (tid < 48)  p_eq = eq_in[_b * 3 + tid];                          \
    } while (0)

    LOAD_TILE((long)blockIdx.x * 16);

    for (int tile = blockIdx.x; tile < N_TILES; tile += GRID) {
        const long base = (long)tile * 16;

        // ---- commit prefetched regs -> LDS (f32->f16 convert for A operands)
        if (tid < 48) eqin_s[tid / 3][tid % 3] = p_eq;
        if (tid < 192) *(float4*)&eh_s[tid / 12][(tid % 12) * 4] = p_eh;
        {
            half4v h; h[0] = (_Float16)p_inv.x; h[1] = (_Float16)p_inv.y;
                      h[2] = (_Float16)p_inv.z; h[3] = (_Float16)p_inv.w;
            *(half4v*)&A_ii[tid >> 4][(tid & 15) * 4] = h;
        }
        {
            half4v h; h[0] = (_Float16)p_hid0.x; h[1] = (_Float16)p_hid0.y;
                      h[2] = (_Float16)p_hid0.z; h[3] = (_Float16)p_hid0.w;
            *(half4v*)&A_ii[tid >> 5][64 + (tid & 31) * 4] = h;
            const int i1 = tid + 256;
            half4v g; g[0] = (_Float16)p_hid1.x; g[1] = (_Float16)p_hid1.y;
                      g[2] = (_Float16)p_hid1.z; g[3] = (_Float16)p_hid1.w;
            *(half4v*)&A_ii[i1 >> 5][64 + (i1 & 31) * 4] = g;
        }
        __syncthreads();                                   // barrier A

        // ---- issue next tile's global loads (consumed at next commit)
        if (tile + GRID < N_TILES) LOAD_TILE((long)(tile + GRID) * 16);

        // ---- build A_rw / A_xn with inline norm recompute
        for (int t = tid; t < 816; t += 256) {
            const int r = t / 51, rem = t % 51;
            const int s = rem / 17, c = rem % 17;
            float x0, x1, x2;
            if (c == 0) { x0 = eqin_s[r][0]; x1 = eqin_s[r][1]; x2 = eqin_s[r][2]; }
            else        { x0 = eh_s[r][c - 1]; x1 = eh_s[r][15 + c]; x2 = eh_s[r][31 + c]; }
            const float a  = fmaf(x0, x0, fmaf(x1, x1, fmaf(x2, x2, 1e-6f)));
            const float rn = __builtin_amdgcn_rcpf(a);
            const float x  = (s == 0) ? x0 : (s == 1) ? x1 : x2;
            A_rw[r][s * 32 + c] = (_Float16)x;
            A_xn[r][s * 32 + c] = (_Float16)(x * rn);
        }
        __syncthreads();                                   // barrier B

        // ---- MFMAs. A-frag: A[m=lane&15][k=(lane>>4)*8+j]
        float4v acc[2] = {{0.f,0.f,0.f,0.f},{0.f,0.f,0.f,0.f}};
        float4v accg   = {0.f,0.f,0.f,0.f};
#pragma unroll
        for (int s = 0; s < 6; ++s) {
            half8 a = *(const half8*)&A_ii[m][8 * q + 32 * s];
            acc[0] = MFMA16(a, wii[0][s], acc[0]);
            acc[1] = MFMA16(a, wii[1][s], acc[1]);
            if (w == 0) accg = MFMA16(a, wdamp[s], accg);   // gate = inv_comb @ W_damp
        }
        const float4v z4 = {0.f,0.f,0.f,0.f};
#pragma unroll
        for (int g = 0; g < 4; ++g) {           // 4 batches per MFMA (rows = 4*bb+s)
            const int arow = 4 * g + (m >> 2);
            const int aoff = (m & 3) * 32 + 8 * q;
            half8 ax = *(const half8*)&A_xn[arow][aoff];
#pragma unroll
            for (int t = 0; t < 2; ++t) {
                float4v L = MFMA16(ax, wl[t], z4);
                float4v R = MFMA16(ax, wr[t], z4);
                // C rows (lane>>4)*4+reg = 4*bb+s : bb=q, s=reg -> s-sum in-register
                proj_s[4 * g + q][32 * w + 16 * t + m] =
                    L[0]*R[0] + L[1]*R[1] + L[2]*R[2];
            }
            if (w == 1) {                        // ee = eq_comb @ W_ee
                half8 ar = *(const half8*)&A_rw[arow][aoff];
                float4v E = MFMA16(ar, wee, z4);
                ee_s[4 * g + q][m]      = E[0];
                ee_s[4 * g + q][16 + m] = E[1];
                ee_s[4 * g + q][32 + m] = E[2];
            }
        }
        if (w == 0) {
#pragma unroll
            for (int r = 0; r < 4; ++r) gate_s[4 * q + r][m] = accg[r];
        }
        __syncthreads();                                   // barrier C

        // ---- out0 epilogue in C-layout: tanh(ii + proj + b) written back
        // into the SAME proj_s slot (no cross-thread hazard)
#pragma unroll
        for (int t = 0; t < 2; ++t) {
            const int col = 32 * w + 16 * t + m;
#pragma unroll
            for (int r = 0; r < 4; ++r) {
                const float x = acc[t][r] + proj_s[4 * q + r][col] + biiv[t];
                const float e = __expf(2.f * x);          // tanh = 1 - 2/(e^{2x}+1)
                proj_s[4 * q + r][col] = 1.f - 2.f * __builtin_amdgcn_rcpf(e + 1.f);
            }
        }
        // ---- out1: ee + eq_hid * gate (exact f32 eq_hid), contiguous
        for (int i = tid; i < 768; i += 256) {
            const int b = i / 48, j = i % 48;
            out1[base * 48 + i] = ee_s[b][j] + eh_s[b][j] * gate_s[b][j & 15];
        }
        __syncthreads();                                   // barrier D

        // ---- out0 coalesced store: 2048 contiguous floats, float4/thread
        {
            const long ob = base * 128;
#pragma unroll
            for (int h = 0; h < 2; ++h) {
                const int idx = (tid + 256 * h) * 4;       // 0..2044 step 4
                const int r = idx >> 7, c = idx & 127;
                float4 v = *(const float4*)&proj_s[r][c];
                *(float4*)&out0[ob + idx] = v;
            }
        }
        // next iteration's LDS writes are ordered by barriers A'/B' after
        // this read of proj_s — no extra barrier needed
    }
#undef LOAD_TILE
}

extern "C" void kernel_launch(void* const* d_in, const int* in_sizes, int n_in,
                              void* d_out, int out_size, void* d_ws, size_t ws_size,
                              hipStream_t stream) {
    const float* inv_in  = (const float*)d_in[0];
    const float* eq_in   = (const float*)d_in[1];
    const float* inv_hid = (const float*)d_in[2];
    const float* eq_hid  = (const float*)d_in[3];
    const float* Wl      = (const float*)d_in[4];
    const float* Wr      = (const float*)d_in[5];
    const float* Wii     = (const float*)d_in[6];
    const float* bii     = (const float*)d_in[7];
    const float* Wee     = (const float*)d_in[8];
    const float* Wd      = (const float*)d_in[9];
    float* o0 = (float*)d_out;
    float* o1 = o0 + (size_t)131072 * 128;
    hipLaunchKernelGGL(rye_elman_kernel, dim3(GRID), dim3(256), 0, stream,
                       inv_in, eq_in, inv_hid, eq_hid, Wl, Wr, Wii, bii, Wee, Wd, o0, o1);
}